// Round 4
// baseline (9849.242 us; speedup 1.0000x reference)
//
#include <hip/hip_runtime.h>
#include <math.h>

#define NBATCH 4096

// compiler-only memory barrier: forces program-order emission of LDS ops and
// reloads after it. Hardware DS pipe is in-order per wave, so this is all
// that's needed for wave-internal LDS write -> cross-lane read chains.
#define WBAR() asm volatile("" ::: "memory")

__device__ __forceinline__ int SW(int r, int c){ return (r<<4) | (((c)+(r))&15); }

__device__ __forceinline__ float wave64_sum(float v){
  #pragma unroll
  for(int off=32; off; off>>=1) v += __shfl_xor(v, off, 64);
  return v;
}

// ---------------------------------------------------------------------------
// LAPACK scalar helpers (single precision, faithful transcriptions)
// ---------------------------------------------------------------------------

__device__ __forceinline__ void slartgf(float f, float g, float* cs, float* sn, float* r){
  if (g == 0.0f){ *cs = 1.0f; *sn = 0.0f; *r = f; }
  else if (f == 0.0f){ *cs = 0.0f; *sn = copysignf(1.0f, g); *r = fabsf(g); }
  else {
    float d = sqrtf(f*f + g*g);
    *cs = fabsf(f)/d;
    float rr = copysignf(d, f);
    *r = rr;
    *sn = g/rr;
  }
}

__device__ __forceinline__ void slas2f(float f, float g, float hh, float* ssmin, float* ssmax){
  float fa=fabsf(f), ga=fabsf(g), ha=fabsf(hh);
  float fhmn=fminf(fa,ha), fhmx=fmaxf(fa,ha);
  if (fhmn == 0.0f){
    *ssmin = 0.0f;
    if (fhmx == 0.0f) *ssmax = ga;
    else { float mx=fmaxf(fhmx,ga), mn=fminf(fhmx,ga); float q=mn/mx; *ssmax = mx*sqrtf(1.0f+q*q); }
  } else {
    if (ga < fhmx){
      float as_=1.0f+fhmn/fhmx;
      float at_=(fhmx-fhmn)/fhmx;
      float au_=(ga/fhmx); au_=au_*au_;
      float c_=2.0f/(sqrtf(as_*as_+au_)+sqrtf(at_*at_+au_));
      *ssmin=fhmn*c_;
      *ssmax=fhmx/c_;
    } else {
      float au_=fhmx/ga;
      if (au_==0.0f){ *ssmin=(fhmn*fhmx)/ga; *ssmax=ga; }
      else {
        float as_=1.0f+fhmn/fhmx;
        float at_=(fhmx-fhmn)/fhmx;
        float t1=as_*au_, t2=at_*au_;
        float c_=1.0f/(sqrtf(1.0f+t1*t1)+sqrtf(1.0f+t2*t2));
        float sm=(fhmn*c_)*au_;
        *ssmin=sm+sm;
        *ssmax=ga/(c_+c_);
      }
    }
  }
}

__device__ __forceinline__ void slasv2f(float f, float g, float hh,
    float* ssmin, float* ssmax, float* snr, float* csr, float* snl, float* csl){
  const float EPS2 = 5.9604644775390625e-08f;
  float ft=f, fa=fabsf(f), ht=hh, ha=fabsf(hh);
  int pmax=1;
  bool swap_=(ha>fa);
  if (swap_){ pmax=3; float tmp=ft; ft=ht; ht=tmp; tmp=fa; fa=ha; ha=tmp; }
  float gt=g, ga=fabsf(g);
  float clt=0.f, crt=0.f, slt=0.f, srt=0.f;
  if (ga==0.0f){ *ssmin=ha; *ssmax=fa; clt=1.f; crt=1.f; slt=0.f; srt=0.f; }
  else {
    bool gasmal=true;
    if (ga>fa){
      pmax=2;
      if ((fa/ga) < EPS2){
        gasmal=false;
        *ssmax=ga;
        if (ha>1.0f) *ssmin=fa/(ga/ha); else *ssmin=(fa/ga)*ha;
        clt=1.f; slt=ht/gt; srt=1.f; crt=ft/gt;
      }
    }
    if (gasmal){
      float d_=fa-ha;
      float l_;
      if (d_==fa) l_=1.0f; else l_=d_/fa;
      float m_=gt/ft;
      float t_=2.0f-l_;
      float mm=m_*m_, tt=t_*t_;
      float s_=sqrtf(tt+mm);
      float r_;
      if (l_==0.0f) r_=fabsf(m_); else r_=sqrtf(l_*l_+mm);
      float a_=0.5f*(s_+r_);
      *ssmin=ha/a_;
      *ssmax=fa*a_;
      if (mm==0.0f){
        if (l_==0.0f) t_=copysignf(2.0f,ft)*copysignf(1.0f,gt);
        else t_=gt/copysignf(d_,ft)+m_/t_;
      } else {
        t_=(m_/(s_+t_)+m_/(r_+l_))*(1.0f+a_);
      }
      l_=sqrtf(t_*t_+4.0f);
      crt=2.0f/l_;
      srt=t_/l_;
      clt=(crt+srt*m_)/a_;
      slt=(ht/ft)*srt/a_;
    }
  }
  if (swap_){ *csl=srt; *snl=crt; *csr=slt; *snr=clt; }
  else { *csl=clt; *snl=slt; *csr=crt; *snr=srt; }
  float tsign=0.f;
  if (pmax==1) tsign=copysignf(1.f,*csr)*copysignf(1.f,*csl)*copysignf(1.f,f);
  if (pmax==2) tsign=copysignf(1.f,*snr)*copysignf(1.f,*csl)*copysignf(1.f,g);
  if (pmax==3) tsign=copysignf(1.f,*snr)*copysignf(1.f,*snl)*copysignf(1.f,hh);
  *ssmax=copysignf(*ssmax,tsign);
  *ssmin=copysignf(*ssmin,tsign*copysignf(1.f,f)*copysignf(1.f,hh));
}

// ---------------------------------------------------------------------------
// Kernel 1: per-batch init — sgesdd path-9t emulation + wd init
// grid 4096, block 64 (1 wave)
// ---------------------------------------------------------------------------
__global__ __launch_bounds__(64) void init_kernel(
    const float* __restrict__ h,
    const float* __restrict__ wd_init,
    float* __restrict__ out_wa,   // [4096][128][16] (b0 slice region)
    float* __restrict__ out_wd)   // [8][4096][16][16]
{
  const int batch = blockIdx.x;
  const int lane  = threadIdx.x;

  __shared__ float A[16][128];
  __shared__ float Lm[16][16];
  __shared__ float VTs[16][16];
  __shared__ float Wtop[16][16];
  __shared__ float Qtop[256];
  __shared__ float tauL[16], tp[16];
  __shared__ float dB[16], eB[16];
  __shared__ float dsh[17];
  __shared__ float esh[17];

  // ---- A = mean over b of h ----
  for(int e0=lane; e0<2048; e0+=64){
    int nn=e0>>7, mmi=e0&127;
    float s=0.f;
    #pragma unroll
    for(int i=0;i<8;i++) s += h[((size_t)(i*NBATCH+batch))*2048 + nn*128 + mmi];
    A[nn][mmi]=s*0.125f;
  }
  __syncthreads();

  // ---- sgelq2 ----
  for(int i=0;i<16;i++){
    float part=0.f;
    for(int j=i+1+lane;j<128;j+=64){ float v=A[i][j]; part+=v*v; }
    float xn2=wave64_sum(part);
    float alpha=A[i][i];
    float tau,beta,scal;
    if (xn2==0.0f){ tau=0.f; beta=alpha; scal=0.f; }
    else {
      beta=-copysignf(sqrtf(alpha*alpha+xn2), alpha);
      tau=(beta-alpha)/beta;
      scal=1.0f/(alpha-beta);
    }
    if (tau!=0.0f){
      for(int j=i+1+lane;j<128;j+=64) A[i][j]*=scal;
    }
    if (lane==0){ A[i][i]=beta; tauL[i]=tau; }
    __syncthreads();
    if (tau!=0.0f){
      for(int r=i+1;r<16;r++){
        float p=0.f;
        for(int j=i+1+lane;j<128;j+=64) p += A[r][j]*A[i][j];
        float w=wave64_sum(p) + A[r][i];
        float tw=tau*w;
        for(int j=i+1+lane;j<128;j+=64) A[r][j]-=tw*A[i][j];
        if (lane==0) A[r][i]-=tw;
      }
    }
    __syncthreads();
  }

  // ---- Q columns 0..15 into registers (rows lane and lane+64) ----
  float qc0[16], qc1[16];
  #pragma unroll
  for(int j=0;j<16;j++){
    float c0 = (lane==j)?1.0f:0.0f;
    float c1 = 0.0f;
    for(int i=0;i<16;i++){
      float tau=tauL[i];
      float p=0.f;
      if (lane>i) p += A[i][lane]*c0;
      else if (lane==i) p += c0;
      p += A[i][64+lane]*c1;
      float w=wave64_sum(p);
      if (tau!=0.0f){
        float tw=tau*w;
        if (lane==i) c0 -= tw;
        else if (lane>i) c0 -= tw*A[i][lane];
        c1 -= tw*A[i][64+lane];
      }
    }
    qc0[j]=c0;
    qc1[j]=c1;
  }
  if (lane<16){
    #pragma unroll
    for(int j=0;j<16;j++) Qtop[lane*16+j]=qc0[j];
  }
  __syncthreads();

  // ---- L (lower triangular 16x16) ----
  for(int e0=lane;e0<256;e0+=64){ int r=e0>>4,c=e0&15; Lm[r][c]=(c<=r)?A[r][c]:0.0f; }
  __syncthreads();

  // ---- sgebd2 on L ----
  for(int i=0;i<16;i++){
    float alpha=Lm[i][i];
    float xn2=0.f;
    for(int r=i+1;r<16;r++){ float v=Lm[r][i]; xn2+=v*v; }
    float tauqi,beta,scal;
    if (xn2==0.0f){ tauqi=0.f; beta=alpha; scal=0.f; }
    else { beta=-copysignf(sqrtf(alpha*alpha+xn2),alpha); tauqi=(beta-alpha)/beta; scal=1.0f/(alpha-beta); }
    __syncthreads();
    if (lane==0){
      dB[i]=beta;
      if (tauqi!=0.0f) for(int r=i+1;r<16;r++) Lm[r][i]*=scal;
    }
    __syncthreads();
    if (tauqi!=0.0f && lane>i && lane<16){
      int c=lane;
      float w=Lm[i][c];
      for(int r=i+1;r<16;r++) w += Lm[r][i]*Lm[r][c];
      float tw=tauqi*w;
      Lm[i][c]-=tw;
      for(int r=i+1;r<16;r++) Lm[r][c]-=tw*Lm[r][i];
    }
    __syncthreads();
    if (i<15){
      float alph2=Lm[i][i+1];
      float yn2=0.f;
      for(int c=i+2;c<16;c++){ float v=Lm[i][c]; yn2+=v*v; }
      float taupi,beta2,scal2;
      if (yn2==0.0f){ taupi=0.f; beta2=alph2; scal2=0.f; }
      else { beta2=-copysignf(sqrtf(alph2*alph2+yn2),alph2); taupi=(beta2-alph2)/beta2; scal2=1.0f/(alph2-beta2); }
      __syncthreads();
      if (lane==0){
        tp[i]=taupi; eB[i]=beta2;
        if (taupi!=0.0f) for(int c=i+2;c<16;c++) Lm[i][c]*=scal2;
      }
      __syncthreads();
      if (taupi!=0.0f && lane>i && lane<16){
        int r=lane;
        float w=Lm[r][i+1];
        for(int c=i+2;c<16;c++) w += Lm[i][c]*Lm[r][c];
        float tw=taupi*w;
        Lm[r][i+1]-=tw;
        for(int c=i+2;c<16;c++) Lm[r][c]-=tw*Lm[i][c];
      }
      __syncthreads();
    } else {
      if (lane==0) tp[i]=0.0f;
      __syncthreads();
    }
  }

  // ---- sbdsqr ('U', n=16, NCVT=16, NRU=0) ----
  if (lane==0){
    for(int k=1;k<=16;k++) dsh[k]=dB[k-1];
    for(int k=1;k<=15;k++) esh[k]=eB[k-1];
  }
  if (lane<16){
    for(int r=0;r<16;r++) VTs[r][lane]=(r==lane)?1.0f:0.0f;
  }
  __syncthreads();
  {
    const float EPSB = 5.9604644775390625e-08f;
    const float UNFL = 1.1754943508222875e-38f;
    const float tolb = 10.0f*EPSB;
    float sminoa;
    {
      sminoa=fabsf(dsh[1]);
      if (sminoa!=0.0f){
        float mu=sminoa;
        for(int k=2;k<=16;k++){
          mu=fabsf(dsh[k])*(mu/(mu+fabsf(esh[k-1])));
          sminoa=fminf(sminoa,mu);
          if (sminoa==0.0f) break;
        }
      }
      sminoa*=0.25f;
    }
    float thresh=fmaxf(tolb*sminoa, 6.0f*256.0f*UNFL);
    int maxitdivn=6*16, iterdivn=0, iter_=-1;
    int oldll=-1, oldm=-1, idir=0;
    int mq=16;
    float sminl=0.0f;
    int guard=0;
    while (guard++ < 4000){
      if (mq<=1) break;
      if (iter_>=16){ iter_-=16; iterdivn++; if (iterdivn>=maxitdivn) break; }
      float smax=fabsf(dsh[mq]);
      int ll=0; bool split=false;
      for(int lll=1;lll<=mq-1;lll++){
        int l2=mq-lll;
        float abss=fabsf(dsh[l2]);
        float abse=fabsf(esh[l2]);
        if (abse<=thresh){ ll=l2; split=true; break; }
        smax=fmaxf(smax,fmaxf(abss,abse));
      }
      if (split){
        if (lane==0) esh[ll]=0.0f;
        __syncthreads();
        if (ll==mq-1){ mq=mq-1; continue; }
        ll=ll+1;
      } else ll=1;
      if (ll==mq-1){
        float sigmn,sigmx,sinr,cosr,sinl_,cosl_;
        slasv2f(dsh[mq-1],esh[mq-1],dsh[mq],&sigmn,&sigmx,&sinr,&cosr,&sinl_,&cosl_);
        __syncthreads();
        if (lane==0){ dsh[mq-1]=sigmx; esh[mq-1]=0.0f; dsh[mq]=sigmn; }
        if (lane<16){
          float x0=VTs[mq-2][lane], y0=VTs[mq-1][lane];
          VTs[mq-2][lane]=cosr*x0+sinr*y0;
          VTs[mq-1][lane]=cosr*y0-sinr*x0;
        }
        __syncthreads();
        mq-=2;
        continue;
      }
      if (ll>oldm || mq<oldll)
        idir=(fabsf(dsh[ll])>=fabsf(dsh[mq]))?1:2;
      bool conv=false;
      if (idir==1){
        if (fabsf(esh[mq-1])<=tolb*fabsf(dsh[mq])){ if(lane==0) esh[mq-1]=0.0f; conv=true; }
        if (!conv){
          float mu=fabsf(dsh[ll]); sminl=mu;
          for(int lll=ll;lll<=mq-1;lll++){
            if (fabsf(esh[lll])<=tolb*mu){ if(lane==0) esh[lll]=0.0f; conv=true; break; }
            mu=fabsf(dsh[lll+1])*(mu/(mu+fabsf(esh[lll])));
            sminl=fminf(sminl,mu);
          }
        }
      } else {
        if (fabsf(esh[ll])<=tolb*fabsf(dsh[ll])){ if(lane==0) esh[ll]=0.0f; conv=true; }
        if (!conv){
          float mu=fabsf(dsh[mq]); sminl=mu;
          for(int lll=mq-1;lll>=ll;lll--){
            if (fabsf(esh[lll])<=tolb*mu){ if(lane==0) esh[lll]=0.0f; conv=true; break; }
            mu=fabsf(dsh[lll])*(mu/(mu+fabsf(esh[lll])));
            sminl=fminf(sminl,mu);
          }
        }
      }
      if (conv){ __syncthreads(); continue; }
      oldll=ll; oldm=mq;
      float shift=0.0f, rdum;
      if (!( 16.0f*tolb*(sminl/smax) <= fmaxf(EPSB, 0.01f*tolb) )){
        float sll;
        if (idir==1){ sll=fabsf(dsh[ll]); slas2f(dsh[mq-1],esh[mq-1],dsh[mq],&shift,&rdum); }
        else        { sll=fabsf(dsh[mq]); slas2f(dsh[ll],esh[ll],dsh[ll+1],&shift,&rdum); }
        if (sll>0.0f){ float q=shift/sll; if (q*q<EPSB) shift=0.0f; }
      }
      iter_ += mq-ll;
      if (shift==0.0f){
        if (idir==1){
          float cs=1.0f, oldcs=1.0f, sn=0.0f, oldsn=0.0f, r1, r2;
          for(int i=ll;i<=mq-1;i++){
            slartgf(dsh[i]*cs, esh[i], &cs, &sn, &r1);
            if (i>ll){ if(lane==0) esh[i-1]=oldsn*r1; }
            slartgf(oldcs*r1, dsh[i+1]*sn, &oldcs, &oldsn, &r2);
            if (lane==0) dsh[i]=r2;
            if (lane<16){
              float lo=VTs[i-1][lane], hi=VTs[i][lane];
              VTs[i][lane]  =cs*hi-sn*lo;
              VTs[i-1][lane]=sn*hi+cs*lo;
            }
            __syncthreads();
          }
          float hval=dsh[mq]*cs;
          float nd=hval*oldcs, ne=hval*oldsn;
          if (lane==0){ dsh[mq]=nd; esh[mq-1]=(fabsf(ne)<=thresh)?0.0f:ne; }
          __syncthreads();
        } else {
          float cs=1.0f, oldcs=1.0f, sn=0.0f, oldsn=0.0f, r1, r2;
          for(int i=mq;i>=ll+1;i--){
            slartgf(dsh[i]*cs, esh[i-1], &cs, &sn, &r1);
            if (i<mq){ if(lane==0) esh[i]=oldsn*r1; }
            slartgf(oldcs*r1, dsh[i-1]*sn, &oldcs, &oldsn, &r2);
            if (lane==0) dsh[i]=r2;
            if (lane<16){
              float lo=VTs[i-2][lane], hi=VTs[i-1][lane];
              float c_=oldcs, s_=-oldsn;
              VTs[i-1][lane]=c_*hi-s_*lo;
              VTs[i-2][lane]=s_*hi+c_*lo;
            }
            __syncthreads();
          }
          float hval=dsh[ll]*cs;
          float nd=hval*oldcs, ne=hval*oldsn;
          if (lane==0){ dsh[ll]=nd; esh[ll]=(fabsf(ne)<=thresh)?0.0f:ne; }
          __syncthreads();
        }
      } else {
        if (idir==1){
          float dll=dsh[ll];
          float f=(fabsf(dll)-shift)*(copysignf(1.0f,dll)+shift/dll);
          float g=esh[ll];
          float cosr,sinr,cosl_,sinl_,r1;
          for(int i=ll;i<=mq-1;i++){
            slartgf(f,g,&cosr,&sinr,&r1);
            if (i>ll){ if(lane==0) esh[i-1]=r1; }
            float di=dsh[i], ei=esh[i], dip=dsh[i+1];
            f=cosr*di+sinr*ei;
            float ei1=cosr*ei-sinr*di;
            g=sinr*dip;
            float dip1=cosr*dip;
            slartgf(f,g,&cosl_,&sinl_,&r1);
            if (lane==0) dsh[i]=r1;
            f=cosl_*ei1+sinl_*dip1;
            float dip2=cosl_*dip1-sinl_*ei1;
            float eip2=0.0f;
            if (i<mq-1){
              float eip=esh[i+1];
              g=sinl_*eip;
              eip2=cosl_*eip;
            }
            if (lane==0){
              esh[i]=ei1;
              dsh[i+1]=dip2;
              if (i<mq-1) esh[i+1]=eip2;
            }
            if (lane<16){
              float lo=VTs[i-1][lane], hi=VTs[i][lane];
              VTs[i][lane]  =cosr*hi-sinr*lo;
              VTs[i-1][lane]=sinr*hi+cosr*lo;
            }
            __syncthreads();
          }
          if (lane==0) esh[mq-1]=(fabsf(f)<=thresh)?0.0f:f;
          __syncthreads();
        } else {
          float dm=dsh[mq];
          float f=(fabsf(dm)-shift)*(copysignf(1.0f,dm)+shift/dm);
          float g=esh[mq-1];
          float cosr,sinr,cosl_,sinl_,r1;
          for(int i=mq;i>=ll+1;i--){
            slartgf(f,g,&cosr,&sinr,&r1);
            if (i<mq){ if(lane==0) esh[i]=r1; }
            float di=dsh[i], eim=esh[i-1], dim=dsh[i-1];
            f=cosr*di+sinr*eim;
            float eim1=cosr*eim-sinr*di;
            g=sinr*dim;
            float dim1=cosr*dim;
            slartgf(f,g,&cosl_,&sinl_,&r1);
            if (lane==0) dsh[i]=r1;
            f=cosl_*eim1+sinl_*dim1;
            float dim2=cosl_*dim1-sinl_*eim1;
            float eim3=0.0f;
            if (i>ll+1){
              float e2=esh[i-2];
              g=sinl_*e2;
              eim3=cosl_*e2;
            }
            if (lane==0){
              esh[i-1]=eim1;
              dsh[i-1]=dim2;
              if (i>ll+1) esh[i-2]=eim3;
            }
            if (lane<16){
              float lo=VTs[i-2][lane], hi=VTs[i-1][lane];
              float c_=cosl_, s_=-sinl_;
              VTs[i-1][lane]=c_*hi-s_*lo;
              VTs[i-2][lane]=s_*hi+c_*lo;
            }
            __syncthreads();
          }
          if (lane==0) esh[ll]=(fabsf(f)<=thresh)?0.0f:f;
          __syncthreads();
        }
      }
    }
    // make singular values positive
    for(int k=1;k<=16;k++){
      float dv=dsh[k];
      if (dv<0.0f){
        if (lane==0) dsh[k]=-dv;
        if (lane<16) VTs[k-1][lane]=-VTs[k-1][lane];
      }
      __syncthreads();
    }
    // sort decreasing
    for(int i=1;i<=15;i++){
      int isub=1; float smn=dsh[1];
      for(int j=2;j<=17-i;j++){ float dj=dsh[j]; if (dj<=smn){ isub=j; smn=dj; } }
      if (isub!=17-i){
        if (lane==0){ dsh[isub]=dsh[17-i]; dsh[17-i]=smn; }
        if (lane<16){ float tv=VTs[isub-1][lane]; VTs[isub-1][lane]=VTs[16-i][lane]; VTs[16-i][lane]=tv; }
      }
      __syncthreads();
    }
  }
  __syncthreads();

  // ---- apply P^T (gebrd right reflectors) ----
  for(int i=14;i>=0;i--){
    float tau=tp[i];
    if (tau!=0.0f && lane<16){
      int r=lane;
      float w=VTs[r][i+1];
      for(int c=i+2;c<16;c++) w += VTs[r][c]*Lm[i][c];
      float tw=tau*w;
      VTs[r][i+1]-=tw;
      for(int c=i+2;c<16;c++) VTs[r][c]-=tw*Lm[i][c];
    }
    __syncthreads();
  }

  // ---- Wtop = VT_L * Q[0:16, 0:16] ----
  for(int e0=lane;e0<256;e0+=64){
    int r=e0>>4, j=e0&15;
    float s=0.f;
    #pragma unroll
    for(int c=0;c<16;c++) s += VTs[r][c]*Qtop[c*16+j];
    Wtop[r][j]=s;
  }
  __syncthreads();

  // ---- wa output: rows lane (Wtop or Q) and lane+64 (Q) ----
  {
    float* wab = out_wa + (size_t)batch*2048;
    #pragma unroll
    for(int j=0;j<16;j++){
      wab[lane*16+j]      = (lane<16)? Wtop[lane][j] : qc0[j];
      wab[(lane+64)*16+j] = qc1[j];
    }
  }

  // ---- wd init scale ----
  float wrow[16];
  #pragma unroll
  for(int c=0;c<16;c++) wrow[c] = (lane<16)? Wtop[lane][c] : qc0[c];
  float* wdL = (float*)Lm;
  float part=0.f;
  for(int i=0;i<8;i++){
    const float* wdi = wd_init + ((size_t)(i*NBATCH+batch))*256;
    __syncthreads();
    for(int e=lane;e<256;e+=64) wdL[e]=wdi[e];
    __syncthreads();
    #pragma unroll
    for(int j=0;j<16;j++){
      float s0=0.f, s1=0.f;
      #pragma unroll
      for(int c=0;c<16;c++){ float wv=wdL[c*16+j]; s0 += wrow[c]*wv; s1 += qc1[c]*wv; }
      part += s0*s0 + s1*s1;
    }
  }
  float fro2=wave64_sum(part);
  float scal2=sqrtf(128.0f/fro2);
  for(int i=0;i<8;i++){
    const float* wdi = wd_init + ((size_t)(i*NBATCH+batch))*256;
    float* wdo = out_wd + ((size_t)(i*NBATCH+batch))*256;
    for(int e=lane;e<256;e+=64) wdo[e]=scal2*wdi[e];
  }
}

// ---------------------------------------------------------------------------
// Kernel 2: per-batch 5-iteration projected gradient ascent
// grid 4096, block 256 (4 waves; wave w owns channels {w, w+4})
// ---------------------------------------------------------------------------
__global__ __launch_bounds__(256,4) void iter_kernel(
    const float* __restrict__ h,
    const float* __restrict__ hyp,
    float* __restrict__ out_obj,
    float* __restrict__ out_wa,
    float* __restrict__ out_wd)
{
  const int batch = blockIdx.x;
  const int t = threadIdx.x;
  const int wave = t>>6, lane = t&63;
  const int r16 = t>>4, c16 = t&15;
  const int ls = lane>>4, cc = lane&15;

  __shared__ float Wf[2048];                 // wa, linear [m][l]
  __shared__ float Uf[2048];                 // u, linear per channel
  __shared__ float Kf[2048];                 // K / phase1a A-scratch, SW per channel
  __shared__ float Wd[2048];                 // wd_t, SW per channel (scal deferred)
  __shared__ __align__(16) float Hs[1024];   // h half-staging / wave scratch
  __shared__ float Gm[256];                  // Gram wa^T wa, linear
  __shared__ float misc[24];                 // 0..7 logdets, 8..15 f_j, 16..19 red

  // ---- per-channel 16x16 chain: t -> cov -> inv(+logdet) -> T1 -> T2 -> K ----
  auto chain_K = [&](int ch, bool wlog){
    float* U = Uf + ch*256;
    float* W = Wd + ch*256;
    float* A = Kf + ch*256;
    float* B = Hs + wave*256;
    #pragma unroll
    for(int q=0;q<4;q++){
      int rr=q*4+ls; float s=0.f;
      #pragma unroll
      for(int k=0;k<16;k++) s += U[rr*16+k]*W[SW(k,cc)];
      A[SW(rr,cc)]=s;
    }
    WBAR();
    #pragma unroll
    for(int q=0;q<4;q++){
      int rr=q*4+ls; float s=(rr==cc)?1.0f:0.0f;
      #pragma unroll
      for(int k=0;k<16;k++) s += A[SW(rr,k)]*A[SW(cc,k)];
      B[SW(rr,cc)]=s;
    }
    WBAR();
    float logacc=0.f;
    for(int k=0;k<16;k++){
      float piv=B[SW(k,k)];
      float pinv=1.0f/piv;
      if (wlog) logacc += logf(piv);
      float rkv=B[SW(k,cc)];
      float ck[4],cu[4];
      #pragma unroll
      for(int q=0;q<4;q++){ int rr=q*4+ls; ck[q]=B[SW(rr,k)]; cu[q]=B[SW(rr,cc)]; }
      WBAR();
      #pragma unroll
      for(int q=0;q<4;q++){
        int rr=q*4+ls; float v;
        if (rr==k) v=(cc==k)?pinv:rkv*pinv;
        else if (cc==k) v=-ck[q]*pinv;
        else v=cu[q]-ck[q]*pinv*rkv;
        B[SW(rr,cc)]=v;
      }
      WBAR();
    }
    if (wlog && lane==0) misc[ch]=logacc;
    // T1 = inv^T u -> A
    #pragma unroll
    for(int q=0;q<4;q++){
      int rr=q*4+ls; float s=0.f;
      #pragma unroll
      for(int k=0;k<16;k++) s += B[SW(k,rr)]*U[k*16+cc];
      A[SW(rr,cc)]=s;
    }
    WBAR();
    // T2 = T1 wd -> B
    #pragma unroll
    for(int q=0;q<4;q++){
      int rr=q*4+ls; float s=0.f;
      #pragma unroll
      for(int k=0;k<16;k++) s += A[SW(rr,k)]*W[SW(k,cc)];
      B[SW(rr,cc)]=s;
    }
    WBAR();
    // K = T2 wd^T -> A
    #pragma unroll
    for(int q=0;q<4;q++){
      int rr=q*4+ls; float s=0.f;
      #pragma unroll
      for(int k=0;k<16;k++) s += B[SW(rr,k)]*W[SW(cc,k)];
      A[SW(rr,cc)]=s;
    }
    WBAR();
  };

  // ---- inner wd step (one wave, channel i).
  // first==true  -> sc = 1 (reference: step 0 uses wd as-is)
  // first==false -> sc = current renorm scale of wd_t under new wa
  auto inner_step = [&](int i, int x, bool first){
    float sc;
    if (first) sc = 1.0f;
    else {
      float fs=0.f;
      #pragma unroll
      for(int j=0;j<8;j++) fs += misc[8+j];
      sc = sqrtf(128.0f/fs);
    }
    float* U = Uf + i*256;
    float* W = Wd + i*256;
    float* A = Hs;
    float* B = Hs + 256;
    #pragma unroll
    for(int q=0;q<4;q++){
      int rr=q*4+ls; float s=0.f;
      #pragma unroll
      for(int k=0;k<16;k++) s += U[rr*16+k]*(sc*W[SW(k,cc)]);
      A[SW(rr,cc)]=s;
    }
    WBAR();
    #pragma unroll
    for(int q=0;q<4;q++){
      int rr=q*4+ls; float s=(rr==cc)?1.0f:0.0f;
      #pragma unroll
      for(int k=0;k<16;k++) s += A[SW(rr,k)]*A[SW(cc,k)];
      B[SW(rr,cc)]=s;
    }
    WBAR();
    for(int k=0;k<16;k++){
      float piv=B[SW(k,k)];
      float pinv=1.0f/piv;
      float rkv=B[SW(k,cc)];
      float ck[4],cu[4];
      #pragma unroll
      for(int q=0;q<4;q++){ int rr=q*4+ls; ck[q]=B[SW(rr,k)]; cu[q]=B[SW(rr,cc)]; }
      WBAR();
      #pragma unroll
      for(int q=0;q<4;q++){
        int rr=q*4+ls; float v;
        if (rr==k) v=(cc==k)?pinv:rkv*pinv;
        else if (cc==k) v=-ck[q]*pinv;
        else v=cu[q]-ck[q]*pinv*rkv;
        B[SW(rr,cc)]=v;
      }
      WBAR();
    }
    // M1 = u^T inv^T -> A
    #pragma unroll
    for(int q=0;q<4;q++){
      int rr=q*4+ls; float s=0.f;
      #pragma unroll
      for(int k=0;k<16;k++) s += U[k*16+rr]*B[SW(cc,k)];
      A[SW(rr,cc)]=s;
    }
    WBAR();
    // M2 = M1 u -> B
    #pragma unroll
    for(int q=0;q<4;q++){
      int rr=q*4+ls; float s=0.f;
      #pragma unroll
      for(int k=0;k<16;k++) s += A[SW(rr,k)]*U[k*16+cc];
      B[SW(rr,cc)]=s;
    }
    WBAR();
    // g, update wd_t[i]
    float hypi = hyp[x*9+i+1];
    float wnew[4];
    #pragma unroll
    for(int q=0;q<4;q++){
      int rr=q*4+ls; float g=0.f;
      #pragma unroll
      for(int k=0;k<16;k++) g += B[SW(rr,k)]*(sc*W[SW(k,cc)]);
      g*=0.125f;
      wnew[q] = sc*W[SW(rr,cc)] + hypi*g;
    }
    WBAR();
    #pragma unroll
    for(int q=0;q<4;q++){ int rr=q*4+ls; W[SW(rr,cc)]=wnew[q]; }
    WBAR();
    // f_i = tr(wdt^T G wdt)
    float part=0.f;
    #pragma unroll
    for(int q=0;q<4;q++){
      int rr=q*4+ls; float gw=0.f;
      #pragma unroll
      for(int k=0;k<16;k++) gw += Gm[rr*16+k]*W[SW(k,cc)];
      part += gw*W[SW(rr,cc)];
    }
    part = wave64_sum(part);
    if (lane==0) misc[8+i]=part;
  };

  // ---- staged u recompute for one (channel, half) ----
  auto stage_and_u = [&](int ch, int half){
    const float4* h4 = (const float4*)(h + ((size_t)(ch*NBATCH+batch))*2048);
    __syncthreads();
    ((float4*)Hs)[t] = h4[half*256+t];
    __syncthreads();
    if ((r16>>3)==half){
      const float4* H4=(const float4*)Hs;
      float s=0.f;
      #pragma unroll
      for(int m4=0;m4<32;m4++){
        float4 hv=H4[(r16&7)*32+m4];
        s += hv.x*Wf[(m4*4+0)*16+c16];
        s += hv.y*Wf[(m4*4+1)*16+c16];
        s += hv.z*Wf[(m4*4+2)*16+c16];
        s += hv.w*Wf[(m4*4+3)*16+c16];
      }
      Uf[ch*256+r16*16+c16]=s;
    }
  };

  // ================= prologue =================
  {
    const float* src = out_wa + (size_t)batch*2048;
    for(int e=t;e<2048;e+=256) Wf[e]=src[e];
    for(int ch=0;ch<8;ch++){
      const float* s2 = out_wd + ((size_t)(ch*NBATCH+batch))*256;
      Wd[ch*256+SW(r16,c16)] = s2[t];
    }
    if (t<8) misc[8+t]=16.0f;   // => fold scale 1.0 at x=0
  }
  __syncthreads();
  for(int ch=0;ch<8;ch++)
    for(int half=0;half<2;half++)
      stage_and_u(ch,half);
  __syncthreads();

  // ================= main loop =================
  for(int x=0;x<5;x++){
    // fold deferred scal into wd_t (wave-local, own channels)
    {
      float fs=0.f;
      #pragma unroll
      for(int j=0;j<8;j++) fs += misc[8+j];
      float scf = sqrtf(128.0f/fs);
      #pragma unroll
      for(int ci=0;ci<2;ci++){
        float* W = Wd + (wave+ci*4)*256;
        #pragma unroll
        for(int q=0;q<4;q++){ int rr=q*4+ls; W[SW(rr,cc)]*=scf; }
      }
      WBAR();
    }
    // phase 1a: per-channel cov -> inv -> K (wave-internal), logdet for obj
    chain_K(wave, true);
    chain_K(wave+4, true);
    __syncthreads();
    if (x>0 && t==0){
      float s=0.f;
      #pragma unroll
      for(int j=0;j<8;j++) s+=misc[j];
      out_obj[(size_t)batch*5+(x-1)]=s*0.125f;
    }
    // phase 1b: F2 = sum_i h_i^T K_i   (registers)
    float a0=0,a1=0,a2=0,a3=0,a4=0,a5=0,a6=0,a7=0;
    {
      int mm=t>>1, l0=(t&1)*8;
      for(int ch=0;ch<8;ch++){
        const float4* h4 = (const float4*)(h + ((size_t)(ch*NBATCH+batch))*2048);
        const float* Kr = Kf + ch*256;
        for(int half=0;half<2;half++){
          __syncthreads();
          ((float4*)Hs)[t] = h4[half*256+t];
          __syncthreads();
          #pragma unroll
          for(int n=0;n<8;n++){
            float hv=Hs[n*128+mm];
            int n8=half*8+n;
            a0 += hv*Kr[SW(n8,l0+0)];
            a1 += hv*Kr[SW(n8,l0+1)];
            a2 += hv*Kr[SW(n8,l0+2)];
            a3 += hv*Kr[SW(n8,l0+3)];
            a4 += hv*Kr[SW(n8,l0+4)];
            a5 += hv*Kr[SW(n8,l0+5)];
            a6 += hv*Kr[SW(n8,l0+6)];
            a7 += hv*Kr[SW(n8,l0+7)];
          }
        }
      }
    }
    // phase 2: wa update + renorm, Gram
    {
      float hyp0 = hyp[x*9]*0.125f;
      int mm=t>>1, l0=(t&1)*8;
      float* F2r=&Wf[mm*16+l0];
      F2r[0]+=hyp0*a0; F2r[1]+=hyp0*a1; F2r[2]+=hyp0*a2; F2r[3]+=hyp0*a3;
      F2r[4]+=hyp0*a4; F2r[5]+=hyp0*a5; F2r[6]+=hyp0*a6; F2r[7]+=hyp0*a7;
      __syncthreads();
      float s=0.f;
      #pragma unroll 8
      for(int m=0;m<128;m++) s += Wf[m*16+r16]*Wf[m*16+c16];
      Gm[t]=s;
      __syncthreads();
      float part=0.f;
      for(int j=0;j<8;j++){
        float gw=0.f;
        #pragma unroll
        for(int k=0;k<16;k++) gw += Gm[r16*16+k]*Wd[j*256+SW(k,c16)];
        part += gw*Wd[j*256+SW(r16,c16)];
      }
      part = wave64_sum(part);
      if (lane==0) misc[16+wave]=part;
      __syncthreads();
      float fro2 = misc[16]+misc[17]+misc[18]+misc[19];
      float scal = sqrtf(128.0f/fro2);
      for(int e=t;e<2048;e+=256) Wf[e]*=scal;
      Gm[t]*=scal*scal;
    }
    __syncthreads();
    // phase 3: recompute u with new wa
    for(int ch=0;ch<8;ch++)
      for(int half=0;half<2;half++)
        stage_and_u(ch,half);
    __syncthreads();
    // f_j init (wave-local own channels) with NEW Gram over wd_t (= folded wd)
    #pragma unroll
    for(int ci=0;ci<2;ci++){
      int ch=wave+ci*4;
      float* W = Wd + ch*256;
      float part=0.f;
      #pragma unroll
      for(int q=0;q<4;q++){
        int rr=q*4+ls; float gw=0.f;
        #pragma unroll
        for(int k=0;k<16;k++) gw += Gm[rr*16+k]*W[SW(k,cc)];
        part += gw*W[SW(rr,cc)];
      }
      part=wave64_sum(part);
      if (lane==0) misc[8+ch]=part;
    }
    __syncthreads();
    // inner sequential wd updates (step 0 uses sc=1: wd as-is, per reference)
    for(int i=0;i<8;i++){
      if (wave==(i&3)) inner_step(i,x,(i==0));
      __syncthreads();
    }
  }

  // ================= epilogue: final obj + outputs =================
  {
    float fs=0.f;
    #pragma unroll
    for(int j=0;j<8;j++) fs += misc[8+j];
    float scf = sqrtf(128.0f/fs);
    #pragma unroll
    for(int ci=0;ci<2;ci++){
      float* W = Wd + (wave+ci*4)*256;
      #pragma unroll
      for(int q=0;q<4;q++){ int rr=q*4+ls; W[SW(rr,cc)]*=scf; }
    }
    WBAR();
  }
  chain_K(wave, true);
  chain_K(wave+4, true);
  __syncthreads();
  if (t==0){
    float s=0.f;
    #pragma unroll
    for(int j=0;j<8;j++) s+=misc[j];
    out_obj[(size_t)batch*5+4]=s*0.125f;
  }
  for(int ch=0;ch<8;ch++){
    float* dst = out_wa + ((size_t)(ch*NBATCH+batch))*2048;
    for(int e=t;e<2048;e+=256) dst[e]=Wf[e];
  }
  for(int ch=0;ch<8;ch++){
    out_wd[((size_t)(ch*NBATCH+batch))*256 + t] = Wd[ch*256+SW(r16,c16)];
  }
}

// ---------------------------------------------------------------------------
extern "C" void kernel_launch(void* const* d_in, const int* in_sizes, int n_in,
                              void* d_out, int out_size, void* d_ws, size_t ws_size,
                              hipStream_t stream)
{
  (void)in_sizes; (void)n_in; (void)d_ws; (void)ws_size; (void)out_size;
  const float* h   = (const float*)d_in[0];
  const float* wdi = (const float*)d_in[1];
  const float* hyp = (const float*)d_in[2];
  float* out = (float*)d_out;
  float* out_obj = out;                                   // 4096*5
  float* out_wa  = out + (size_t)NBATCH*5;                // 8*4096*128*16
  float* out_wd  = out_wa + (size_t)8*NBATCH*128*16;      // 8*4096*16*16

  init_kernel<<<NBATCH, 64, 0, stream>>>(h, wdi, out_wa, out_wd);
  iter_kernel<<<NBATCH, 256, 0, stream>>>(h, hyp, out_obj, out_wa, out_wd);
}